// Round 10
// baseline (47.815 us; speedup 1.0000x reference)
//
#include <hip/hip_runtime.h>

// ROIAlign (aligned=True, TF crop_and_resize semantics), NHWC fp32.
// inputs: [2,100,100,256] f32; boxes: [1024,4] f32 (x0,y0,x1,y1);
// box_inds: [1024] i32; out: [1024,7,7,256] f32.
//
// Round-10 structure (2 kernels):
//  P  prep (1 block x 1024): ballot-sort boxes by (image*4 + y-band) into
//     LDS (wave-0 shuffle scan, 3 barriers), then the same threads compute
//     all 14336 per-slot row/col metas item-major (coalesced 32 B records):
//       rmeta[slot*7+oy]: off.x = abs input row base | (nr-1),
//                         off.y = output base (perm FOLDED: (b*49+oy*7)*256),
//                         w = wr * 0.25 (zero-padded)
//       cmeta[slot*7+ox]: off.x = c0*256 | (nc-1), w = wc (zero-padded)
//     Both dims folded to CONTIGUOUS index ranges (clamp+validity in weights),
//     so corner (i,j) = base + i*25600 + j*256 with compile-time offsets.
//  M  main: ONE WAVE PER OUTPUT PIXEL (50176 waves). Per wave: two
//     independent 32 B uniform meta loads -> readfirstlane(sel) -> 16-case
//     switch -> NR*NC back-to-back f32x4 loads -> FMA -> NT store.

constexpr int   H_IN  = 100;
constexpr int   W_IN  = 100;
constexpr int   C_IN  = 256;
constexpr int   OUT_H = 7;
constexpr int   OUT_W = 7;
constexpr int   NPIX  = OUT_H * OUT_W;   // 49
constexpr int   NBOX  = 1024;
constexpr float SCALE = 0.125f;

typedef float f32x4 __attribute__((ext_vector_type(4)));

struct Meta { int4 off; float4 w; };     // 32 B

// ws layout: rmeta Meta[7168] @0 ; cmeta Meta[7168] @229376
constexpr int CMETA_OFF = 7168 * 32;

// ---------------- contiguous fold of 2 bilinear samples --------------------
// Sample valid iff coord in [0, LIM-1]; indices floor/floor+1 clamped to
// [0, LIM-1]. Output: contiguous [c0, c0+n), n in 1..4, zero-padded weights;
// invalid samples contribute 0. (Verified rounds 8/9: absmax 0.0078.)
__device__ __forceinline__ void fold_dim(float s0, float step, int LIM,
                                         int& c0, int& n, float* w)
{
    float s[2] = { s0, s0 + step };
    int   fl[2]; float t[2]; bool val[2];
    int lo = 0x7fffffff, hi = -0x7fffffff;
#pragma unroll
    for (int k = 0; k < 2; ++k) {
        const float f = floorf(s[k]);
        fl[k]  = (int)f;
        t[k]   = s[k] - f;
        val[k] = (s[k] >= 0.0f && s[k] <= (float)(LIM - 1));
        if (val[k]) {
            lo = min(lo, fl[k]);
            hi = max(hi, min(fl[k] + 1, LIM - 1));
        }
    }
    w[0] = w[1] = w[2] = w[3] = 0.0f;
    if (lo > hi) {                     // no valid sample: degenerate, weight 0
        c0 = min(max(fl[0], 0), LIM - 1);
        n  = 1;
        return;
    }
    c0 = lo;
    n  = hi - lo + 1;                  // <= 4 (step <= 1.79)
#pragma unroll
    for (int k = 0; k < 2; ++k) {
        if (val[k]) {
            w[fl[k] - lo]                    += 1.0f - t[k];
            w[min(fl[k] + 1, LIM - 1) - lo]  += t[k];
        }
    }
}

// ---------------- kernel P: sort + all metadata (1 block, 1024 threads) ----
__global__ __launch_bounds__(1024) void prep_kernel(
    const float* __restrict__ boxes,
    const int*   __restrict__ box_inds,
    Meta*        __restrict__ rmeta,
    Meta*        __restrict__ cmeta)
{
    const int tid  = threadIdx.x;
    const int wave = tid >> 6;
    const int lane = tid & 63;

    __shared__ int whist[16][8];
    __shared__ int sc[128];            // exclusive scan, bin-major (k*16 + w)
    __shared__ int sperm[NBOX];        // slot -> box

    // --- bin = image*4 + y-band of box center ---
    const float by0 = boxes[tid * 4 + 1] * SCALE;
    const float by1 = boxes[tid * 4 + 3] * SCALE;
    const float cy  = 0.5f * (by0 + by1);
    int band = (int)(cy * (1.0f / 25.0f));
    band = min(max(band, 0), 3);
    const int bin = box_inds[tid] * 4 + band;   // 0..7

    int wrank = 0;
    const unsigned long long ltmask = (lane == 63) ? ~0ull >> 1
                                                   : (1ull << lane) - 1;
#pragma unroll
    for (int k = 0; k < 8; ++k) {
        const unsigned long long bal = __ballot(bin == k);
        if (bin == k) wrank = __popcll(bal & ltmask);
        if (lane == 0) whist[wave][k] = __popcll(bal);
    }
    __syncthreads();

    // --- wave 0: shuffle-scan the 128 bin-major entries (no extra barriers)
    if (wave == 0) {
        const int e0 = 2 * lane, e1 = 2 * lane + 1;
        const int a = whist[e0 & 15][e0 >> 4];
        const int bq = whist[e1 & 15][e1 >> 4];
        int v = a + bq;
        int incl = v;
#pragma unroll
        for (int d = 1; d < 64; d <<= 1) {
            const int t = __shfl_up(incl, d, 64);
            if (lane >= d) incl += t;
        }
        const int base = incl - v;     // exclusive base for e0
        sc[e0] = base;
        sc[e1] = base + a;
    }
    __syncthreads();

    sperm[sc[bin * 16 + wave] + wrank] = tid;
    __syncthreads();

    // --- metas, item-major: item = k*1024 + tid, 14336 = 14*1024 exactly ---
#pragma unroll 1
    for (int k = 0; k < 14; ++k) {
        const int item = k * 1024 + tid;
        const int slot = item / 14;
        const int d    = item - slot * 14;

        const int b = sperm[slot];
        const int n = box_inds[b];
        const float4 bx = ((const float4*)boxes)[b];
        const float x0 = bx.x * SCALE, y0 = bx.y * SCALE;
        const float x1 = bx.z * SCALE, y1 = bx.w * SCALE;
        const float sw = (x1 - x0) * (1.0f / 14.0f);
        const float sh = (y1 - y0) * (1.0f / 14.0f);

        int c0, cnt; float wgt[4];
        Meta m;
        m.off.z = 0; m.off.w = 0;
        if (d < 7) {                   // row meta, oy = d
            fold_dim(y0 + sh * ((float)(d * 2) + 0.5f) - 0.5f, sh, H_IN,
                     c0, cnt, wgt);
            m.off.x = (n * (H_IN * W_IN * C_IN) + c0 * (W_IN * C_IN)) | (cnt - 1);
            m.off.y = (b * NPIX + d * OUT_W) * C_IN;    // output base, perm folded
            m.w.x = wgt[0] * 0.25f; m.w.y = wgt[1] * 0.25f;
            m.w.z = wgt[2] * 0.25f; m.w.w = wgt[3] * 0.25f;
            rmeta[slot * 7 + d] = m;
        } else {                       // col meta, ox = d-7
            fold_dim(x0 + sw * ((float)((d - 7) * 2) + 0.5f) - 0.5f, sw, W_IN,
                     c0, cnt, wgt);
            m.off.x = (c0 * C_IN) | (cnt - 1);
            m.off.y = 0;
            m.w.x = wgt[0]; m.w.y = wgt[1]; m.w.z = wgt[2]; m.w.w = wgt[3];
            cmeta[slot * 7 + (d - 7)] = m;
        }
    }
}

// ---------------- gather: NR x NC corners at compile-time offsets ----------
template<int NR, int NC>
__device__ __forceinline__ f32x4 gather(const float* __restrict__ src,
                                        const float* wr, const float* wc)
{
    f32x4 v[NR][NC];
#pragma unroll
    for (int i = 0; i < NR; ++i)
#pragma unroll
        for (int j = 0; j < NC; ++j)
            v[i][j] = *(const f32x4*)(src + i * (W_IN * C_IN) + j * C_IN);

    f32x4 acc = {0.f, 0.f, 0.f, 0.f};
#pragma unroll
    for (int i = 0; i < NR; ++i)
#pragma unroll
        for (int j = 0; j < NC; ++j)
            acc += v[i][j] * (wr[i] * wc[j]);
    return acc;
}

// ---------------- kernel M: one wave per pixel -----------------------------
__global__ __launch_bounds__(256) void roi_align_kernel(
    const float* __restrict__ inputs,
    const Meta*  __restrict__ rmeta,
    const Meta*  __restrict__ cmeta,
    float*       __restrict__ out)
{
    const int lane = threadIdx.x & 63;
    const int sub  = __builtin_amdgcn_readfirstlane(threadIdx.x >> 6);

    // XCD-chunked swizzle: grid = 12544 (div by 8); consecutive sorted pixels
    // land on the same XCD.
    const int nchunk = gridDim.x >> 3;
    const int lbid   = (blockIdx.x & 7) * nchunk + (blockIdx.x >> 3);
    const int p      = lbid * 4 + sub;           // sorted pixel id [0, 50176)

    const int slot = p / NPIX;
    const int rem  = p - slot * NPIX;
    const int oy   = (rem * 37) >> 8;            // exact /7 for 0..48
    const int ox   = rem - oy * 7;

    const Meta rm = rmeta[slot * 7 + oy];        // 32 B uniform load
    const Meta cm = cmeta[slot * 7 + ox];        // 32 B uniform load (independent)

    const int rpk = __builtin_amdgcn_readfirstlane(rm.off.x);
    const int cpk = __builtin_amdgcn_readfirstlane(cm.off.x);
    const int sel = (rpk & 3) * 4 + (cpk & 3);

    const float wr[4] = { rm.w.x, rm.w.y, rm.w.z, rm.w.w };
    const float wc[4] = { cm.w.x, cm.w.y, cm.w.z, cm.w.w };

    const float* src = inputs + (rpk & ~3) + (cpk & ~3) + lane * 4;

    f32x4 acc;
    switch (sel) {
        case 0:  acc = gather<1, 1>(src, wr, wc); break;
        case 1:  acc = gather<1, 2>(src, wr, wc); break;
        case 2:  acc = gather<1, 3>(src, wr, wc); break;
        case 3:  acc = gather<1, 4>(src, wr, wc); break;
        case 4:  acc = gather<2, 1>(src, wr, wc); break;
        case 5:  acc = gather<2, 2>(src, wr, wc); break;
        case 6:  acc = gather<2, 3>(src, wr, wc); break;
        case 7:  acc = gather<2, 4>(src, wr, wc); break;
        case 8:  acc = gather<3, 1>(src, wr, wc); break;
        case 9:  acc = gather<3, 2>(src, wr, wc); break;
        case 10: acc = gather<3, 3>(src, wr, wc); break;
        case 11: acc = gather<3, 4>(src, wr, wc); break;
        case 12: acc = gather<4, 1>(src, wr, wc); break;
        case 13: acc = gather<4, 2>(src, wr, wc); break;
        case 14: acc = gather<4, 3>(src, wr, wc); break;
        default: acc = gather<4, 4>(src, wr, wc); break;
    }

    float* op = out + rm.off.y + ox * C_IN + lane * 4;
    __builtin_nontemporal_store(acc, (f32x4*)op);
}

extern "C" void kernel_launch(void* const* d_in, const int* in_sizes, int n_in,
                              void* d_out, int out_size, void* d_ws, size_t ws_size,
                              hipStream_t stream) {
    const float* inputs   = (const float*)d_in[0];
    const float* boxes    = (const float*)d_in[1];
    const int*   box_inds = (const int*)d_in[2];
    float*       out      = (float*)d_out;

    Meta* rmeta = (Meta*)d_ws;
    Meta* cmeta = (Meta*)((char*)d_ws + CMETA_OFF);

    prep_kernel<<<1, NBOX, 0, stream>>>(boxes, box_inds, rmeta, cmeta);

    const int blocks = NBOX * NPIX / 4;          // 12544
    roi_align_kernel<<<blocks, 256, 0, stream>>>(inputs, rmeta, cmeta, out);
}

// Round 11
// 31.150 us; speedup vs baseline: 1.5350x; 1.5350x over previous
//
#include <hip/hip_runtime.h>

// ROIAlign (aligned=True, TF crop_and_resize semantics), NHWC fp32.
// inputs: [2,100,100,256] f32; boxes: [1024,4] f32 (x0,y0,x1,y1);
// box_inds: [1024] i32; out: [1024,7,7,256] f32.
//
// Round-11 structure (3 kernels — R7 skeleton + R10 main):
//  A  sort_boxes (1 block): ballot-sort boxes by (image*4 + y-band) -> perm;
//     wave-0 shuffle scan (no serial 128-iter loop).
//  A2 meta (56 x 256): per sorted slot, 7 row + 7 col metas:
//       rmeta: off.x = abs input row base | (nr-1),
//              off.y = output base (perm folded), w = wr*0.25 (zero-padded)
//       cmeta: off.x = c0*256 | (nc-1), w = wc (zero-padded)
//     Both dims folded to CONTIGUOUS ranges (clamp+validity in weights), so
//     corner (i,j) = base + i*25600 + j*256 with compile-time offsets.
//  M  main: ONE WAVE PER OUTPUT PIXEL (50176 waves). Per wave: two
//     independent 32 B uniform meta loads -> readfirstlane(sel) -> 16-case
//     switch -> NR*NC back-to-back f32x4 loads -> FMA -> NT store.

constexpr int   H_IN  = 100;
constexpr int   W_IN  = 100;
constexpr int   C_IN  = 256;
constexpr int   OUT_H = 7;
constexpr int   OUT_W = 7;
constexpr int   NPIX  = OUT_H * OUT_W;   // 49
constexpr int   NBOX  = 1024;
constexpr float SCALE = 0.125f;

typedef float f32x4 __attribute__((ext_vector_type(4)));

struct Meta { int4 off; float4 w; };     // 32 B

// ws layout: perm int[1024] @0 ; rmeta Meta[7168] @4096 ; cmeta Meta[7168]
constexpr int RMETA_OFF = 4096;
constexpr int CMETA_OFF = 4096 + 7168 * 32;

// ---------------- kernel A: spatial box sort (1 block, 1024 threads) -------
__global__ __launch_bounds__(1024) void sort_boxes_kernel(
    const float* __restrict__ boxes,
    const int*   __restrict__ box_inds,
    int*         __restrict__ perm)
{
    const int tid  = threadIdx.x;
    const int wave = tid >> 6;
    const int lane = tid & 63;

    __shared__ int whist[16][8];
    __shared__ int sc[128];            // exclusive scan, bin-major (k*16 + w)

    const float by0 = boxes[tid * 4 + 1] * SCALE;
    const float by1 = boxes[tid * 4 + 3] * SCALE;
    const float cy  = 0.5f * (by0 + by1);
    int band = (int)(cy * (1.0f / 25.0f));
    band = min(max(band, 0), 3);
    const int bin = box_inds[tid] * 4 + band;   // 0..7

    int wrank = 0;
    const unsigned long long ltmask = (lane == 63) ? ~0ull >> 1
                                                   : (1ull << lane) - 1;
#pragma unroll
    for (int k = 0; k < 8; ++k) {
        const unsigned long long bal = __ballot(bin == k);
        if (bin == k) wrank = __popcll(bal & ltmask);
        if (lane == 0) whist[wave][k] = __popcll(bal);
    }
    __syncthreads();

    // wave 0: shuffle-scan of the 128 bin-major entries (verified round 10)
    if (wave == 0) {
        const int e0 = 2 * lane, e1 = 2 * lane + 1;
        const int a  = whist[e0 & 15][e0 >> 4];
        const int bq = whist[e1 & 15][e1 >> 4];
        int v = a + bq;
        int incl = v;
#pragma unroll
        for (int d = 1; d < 64; d <<= 1) {
            const int t = __shfl_up(incl, d, 64);
            if (lane >= d) incl += t;
        }
        const int base = incl - v;     // exclusive base for e0
        sc[e0] = base;
        sc[e1] = base + a;
    }
    __syncthreads();

    perm[sc[bin * 16 + wave] + wrank] = tid;
}

// ---------------- contiguous fold of 2 bilinear samples --------------------
// Sample valid iff coord in [0, LIM-1]; indices floor/floor+1 clamped to
// [0, LIM-1]. Output: contiguous [c0, c0+n), n in 1..4, zero-padded weights;
// invalid samples contribute 0. (Verified rounds 8/9/10: absmax 0.0078.)
__device__ __forceinline__ void fold_dim(float s0, float step, int LIM,
                                         int& c0, int& n, float* w)
{
    float s[2] = { s0, s0 + step };
    int   fl[2]; float t[2]; bool val[2];
    int lo = 0x7fffffff, hi = -0x7fffffff;
#pragma unroll
    for (int k = 0; k < 2; ++k) {
        const float f = floorf(s[k]);
        fl[k]  = (int)f;
        t[k]   = s[k] - f;
        val[k] = (s[k] >= 0.0f && s[k] <= (float)(LIM - 1));
        if (val[k]) {
            lo = min(lo, fl[k]);
            hi = max(hi, min(fl[k] + 1, LIM - 1));
        }
    }
    w[0] = w[1] = w[2] = w[3] = 0.0f;
    if (lo > hi) {                     // no valid sample: degenerate, weight 0
        c0 = min(max(fl[0], 0), LIM - 1);
        n  = 1;
        return;
    }
    c0 = lo;
    n  = hi - lo + 1;                  // <= 4 (step <= 1.79)
#pragma unroll
    for (int k = 0; k < 2; ++k) {
        if (val[k]) {
            w[fl[k] - lo]                    += 1.0f - t[k];
            w[min(fl[k] + 1, LIM - 1) - lo]  += t[k];
        }
    }
}

// ---------------- kernel A2: per-slot metadata (56 blocks x 256) -----------
__global__ __launch_bounds__(256) void meta_kernel(
    const float* __restrict__ boxes,
    const int*   __restrict__ box_inds,
    const int*   __restrict__ perm,
    Meta*        __restrict__ rmeta,
    Meta*        __restrict__ cmeta)
{
    const int t = blockIdx.x * 256 + threadIdx.x;   // 0..14335
    if (t >= NBOX * 14) return;
    const int slot = t / 14;
    const int d    = t - slot * 14;

    const int b = perm[slot];
    const int n = box_inds[b];

    const float4 bx = ((const float4*)boxes)[b];
    const float x0 = bx.x * SCALE, y0 = bx.y * SCALE;
    const float x1 = bx.z * SCALE, y1 = bx.w * SCALE;
    const float sw = (x1 - x0) * (1.0f / 14.0f);
    const float sh = (y1 - y0) * (1.0f / 14.0f);

    int c0, cnt; float wgt[4];
    Meta m;
    m.off.z = 0; m.off.w = 0;
    if (d < 7) {                       // row meta, oy = d
        fold_dim(y0 + sh * ((float)(d * 2) + 0.5f) - 0.5f, sh, H_IN,
                 c0, cnt, wgt);
        m.off.x = (n * (H_IN * W_IN * C_IN) + c0 * (W_IN * C_IN)) | (cnt - 1);
        m.off.y = (b * NPIX + d * OUT_W) * C_IN;    // output base, perm folded
        m.w.x = wgt[0] * 0.25f; m.w.y = wgt[1] * 0.25f;
        m.w.z = wgt[2] * 0.25f; m.w.w = wgt[3] * 0.25f;
        rmeta[slot * 7 + d] = m;
    } else {                           // col meta, ox = d-7
        fold_dim(x0 + sw * ((float)((d - 7) * 2) + 0.5f) - 0.5f, sw, W_IN,
                 c0, cnt, wgt);
        m.off.x = (c0 * C_IN) | (cnt - 1);
        m.off.y = 0;
        m.w.x = wgt[0]; m.w.y = wgt[1]; m.w.z = wgt[2]; m.w.w = wgt[3];
        cmeta[slot * 7 + (d - 7)] = m;
    }
}

// ---------------- gather: NR x NC corners at compile-time offsets ----------
template<int NR, int NC>
__device__ __forceinline__ f32x4 gather(const float* __restrict__ src,
                                        const float* wr, const float* wc)
{
    f32x4 v[NR][NC];
#pragma unroll
    for (int i = 0; i < NR; ++i)
#pragma unroll
        for (int j = 0; j < NC; ++j)
            v[i][j] = *(const f32x4*)(src + i * (W_IN * C_IN) + j * C_IN);

    f32x4 acc = {0.f, 0.f, 0.f, 0.f};
#pragma unroll
    for (int i = 0; i < NR; ++i)
#pragma unroll
        for (int j = 0; j < NC; ++j)
            acc += v[i][j] * (wr[i] * wc[j]);
    return acc;
}

// ---------------- kernel M: one wave per pixel -----------------------------
__global__ __launch_bounds__(256) void roi_align_kernel(
    const float* __restrict__ inputs,
    const Meta*  __restrict__ rmeta,
    const Meta*  __restrict__ cmeta,
    float*       __restrict__ out)
{
    const int lane = threadIdx.x & 63;
    const int sub  = __builtin_amdgcn_readfirstlane(threadIdx.x >> 6);

    // XCD-chunked swizzle: grid = 12544 (div by 8); consecutive sorted pixels
    // land on the same XCD.
    const int nchunk = gridDim.x >> 3;
    const int lbid   = (blockIdx.x & 7) * nchunk + (blockIdx.x >> 3);
    const int p      = lbid * 4 + sub;           // sorted pixel id [0, 50176)

    const int slot = p / NPIX;
    const int rem  = p - slot * NPIX;
    const int oy   = (rem * 37) >> 8;            // exact /7 for 0..48
    const int ox   = rem - oy * 7;

    const Meta rm = rmeta[slot * 7 + oy];        // 32 B uniform load
    const Meta cm = cmeta[slot * 7 + ox];        // 32 B uniform load (independent)

    const int rpk = __builtin_amdgcn_readfirstlane(rm.off.x);
    const int cpk = __builtin_amdgcn_readfirstlane(cm.off.x);
    const int sel = (rpk & 3) * 4 + (cpk & 3);

    const float wr[4] = { rm.w.x, rm.w.y, rm.w.z, rm.w.w };
    const float wc[4] = { cm.w.x, cm.w.y, cm.w.z, cm.w.w };

    const float* src = inputs + (rpk & ~3) + (cpk & ~3) + lane * 4;

    f32x4 acc;
    switch (sel) {
        case 0:  acc = gather<1, 1>(src, wr, wc); break;
        case 1:  acc = gather<1, 2>(src, wr, wc); break;
        case 2:  acc = gather<1, 3>(src, wr, wc); break;
        case 3:  acc = gather<1, 4>(src, wr, wc); break;
        case 4:  acc = gather<2, 1>(src, wr, wc); break;
        case 5:  acc = gather<2, 2>(src, wr, wc); break;
        case 6:  acc = gather<2, 3>(src, wr, wc); break;
        case 7:  acc = gather<2, 4>(src, wr, wc); break;
        case 8:  acc = gather<3, 1>(src, wr, wc); break;
        case 9:  acc = gather<3, 2>(src, wr, wc); break;
        case 10: acc = gather<3, 3>(src, wr, wc); break;
        case 11: acc = gather<3, 4>(src, wr, wc); break;
        case 12: acc = gather<4, 1>(src, wr, wc); break;
        case 13: acc = gather<4, 2>(src, wr, wc); break;
        case 14: acc = gather<4, 3>(src, wr, wc); break;
        default: acc = gather<4, 4>(src, wr, wc); break;
    }

    float* op = out + rm.off.y + ox * C_IN + lane * 4;
    __builtin_nontemporal_store(acc, (f32x4*)op);
}

extern "C" void kernel_launch(void* const* d_in, const int* in_sizes, int n_in,
                              void* d_out, int out_size, void* d_ws, size_t ws_size,
                              hipStream_t stream) {
    const float* inputs   = (const float*)d_in[0];
    const float* boxes    = (const float*)d_in[1];
    const int*   box_inds = (const int*)d_in[2];
    float*       out      = (float*)d_out;

    int*  perm  = (int*)d_ws;
    Meta* rmeta = (Meta*)((char*)d_ws + RMETA_OFF);
    Meta* cmeta = (Meta*)((char*)d_ws + CMETA_OFF);

    sort_boxes_kernel<<<1, NBOX, 0, stream>>>(boxes, box_inds, perm);
    meta_kernel<<<56, 256, 0, stream>>>(boxes, box_inds, perm, rmeta, cmeta);

    const int blocks = NBOX * NPIX / 4;          // 12544
    roi_align_kernel<<<blocks, 256, 0, stream>>>(inputs, rmeta, cmeta, out);
}